// Round 2
// baseline (180.637 us; speedup 1.0000x reference)
//
#include <hip/hip_runtime.h>
#include <stdint.h>

#define BATCH 32768
#define DIM   512
#define KCLS  512

typedef __bf16    bf16x8 __attribute__((ext_vector_type(8)));
typedef float     f32x4  __attribute__((ext_vector_type(4)));
typedef float     f32x8  __attribute__((ext_vector_type(8)));
typedef uint16_t  u16x8  __attribute__((ext_vector_type(8)));

__device__ __forceinline__ uint16_t f2bf(float f) {
    // RTNE fp32 -> bf16
    uint32_t u = __float_as_uint(f);
    u += 0x7FFFu + ((u >> 16) & 1u);
    return (uint16_t)(u >> 16);
}

#define MFMA(a, b, c) __builtin_amdgcn_mfma_f32_16x16x32_bf16((a), (b), (c), 0, 0, 0)

// ---------------------------------------------------------------------------
// Prep: means (K x D fp32) -> bf16 pre-swizzled into MFMA B-fragment order.
// B-frag for mfma_f32_16x16x32_bf16: B[k = 8*(lane>>4)+j][n = lane&15].
// Bsw layout: index = (((c16*16 + ch)*64) + lane)*8, col = 16*c16 + (lane&15),
// k = 32*ch + 8*(lane>>4) + j.  Also computes inv_var/alpha/beta per class.
// ---------------------------------------------------------------------------
__global__ __launch_bounds__(256) void gmm_prep(
    const float* __restrict__ means,
    const float* __restrict__ log_vars,
    const float* __restrict__ log_weights,
    uint16_t* __restrict__ Bsw,
    float* __restrict__ invv_a,
    float* __restrict__ alpha_a,
    float* __restrict__ beta_a)
{
    const int k = blockIdx.x * 4 + (threadIdx.x >> 6);  // class index
    const int l = threadIdx.x & 63;                     // lane: elems 8l..8l+7

    const float* mrow = means + (size_t)k * DIM + l * 8;
    f32x4 v0 = *(const f32x4*)(mrow);
    f32x4 v1 = *(const f32x4*)(mrow + 4);

    u16x8 pk;
    pk[0] = f2bf(v0[0]); pk[1] = f2bf(v0[1]); pk[2] = f2bf(v0[2]); pk[3] = f2bf(v0[3]);
    pk[4] = f2bf(v1[0]); pk[5] = f2bf(v1[1]); pk[6] = f2bf(v1[2]); pk[7] = f2bf(v1[3]);

    const int c16 = k >> 4, r = k & 15, ch = l >> 2, hh = l & 3;
    *(u16x8*)(Bsw + ((((c16 * 16) + ch) * 64) + (hh * 16 + r)) * 8) = pk;

    float sq = v0[0]*v0[0] + v0[1]*v0[1] + v0[2]*v0[2] + v0[3]*v0[3]
             + v1[0]*v1[0] + v1[1]*v1[1] + v1[2]*v1[2] + v1[3]*v1[3];
    #pragma unroll
    for (int m = 1; m <= 32; m <<= 1) sq += __shfl_xor(sq, m);

    if (l == 0) {
        const float lv = log_vars[k];
        const float iv = __expf(-lv);
        invv_a[k]  = iv;
        alpha_a[k] = -0.5f * iv;
        beta_a[k]  = -0.5f * (sq * iv + (float)DIM * lv) + log_weights[k];
    }
}

// ---------------------------------------------------------------------------
// Main fused kernel, R6.
// Post-mortem R5: 64-row/256-thr tile halved B L2 traffic but VGPR 128+AGPR
// and 68KB LDS dropped residency 16 -> 8 waves/CU; MfmaUtil/VALUBusy FELL.
// Diagnosis: latency/TLP-bound, phase-serialized (avg HBM BW 2.0 TB/s vs
// 105 MB mandatory traffic explains dur almost exactly).
// R6 structure:
//   * 512 thr (8 waves), 64 rows/block, wave owns 64 cols x 64 rows:
//     acc[4][4] = 64 VGPR, B dbuf 32, A frags <=16 live -> target <=128 VGPR
//     via __launch_bounds__(512,4) -> 2 blocks x 8 waves = 16 waves/CU
//     (restores R4 TLP) while keeping B L2 traffic halved (256 MB).
//   * x-staging FUSED into the K-loop (canonical stage-next-while-compute):
//     iter p MFMAs chunk-pair p from LDS while loading/converting/writing
//     chunk-pair p+1. Spreads the 64KB/block HBM read across the K-loop so
//     HBM, L2(B) and MFMA pipes run concurrently. 1 barrier/pair, no LDS
//     aliasing (all 16 chunks resident in 64KB As).
// ---------------------------------------------------------------------------
__global__ __launch_bounds__(512, 4) void gmm_main(
    const float* __restrict__ x,
    const uint16_t* __restrict__ Bsw,
    const float* __restrict__ invv_a,
    const float* __restrict__ alpha_a,
    const float* __restrict__ beta_a,
    float* __restrict__ out)
{
    __shared__ uint16_t As[32768];   // 64 KB: 64 rows x 512 k, A-frag order
    __shared__ float xsq_lds[64];
    __shared__ float pmax[8][64];
    __shared__ float psum[8][64];

    const int t    = threadIdx.x;
    const int w    = t >> 6;        // wave -> col group (64 cols)
    const int lane = t & 63;
    const int r16  = lane & 15;
    const int h    = lane >> 4;
    const int row0 = blockIdx.x * 64;

    // staging identity: thread t stages row sr, k-octets o = 8p + oin
    const int sr = t >> 3, oin = t & 7;
    const int s_rt = sr >> 4, s_r16 = sr & 15;
    const float* xr = x + (size_t)(row0 + sr) * DIM;
    // As idx16 for (chunk c, rt, hh, r16) = ((c*4 + rt)*64 + hh*16 + r16)*8
    // with c = 2p + (oin>>2), hh = oin&3 -> per-pair stride 4096 (u16 units)
    uint16_t* wslot = As + (((((oin >> 2) * 4 + s_rt) * 64) + (oin & 3) * 16 + s_r16) * 8);

    const uint16_t* bb = Bsw + (size_t)w * 32768 + (size_t)lane * 8;
    const uint16_t* ab = As + (size_t)lane * 8;

    float xsq_p = 0.f;
    bf16x8 Ba[4], Bb[4];
    f32x8 xv;

    // ---- prologue: stage pair 0, prefetch B chunk 0 ----
    {
        xv = *(const f32x8*)(xr + 8 * oin);
        #pragma unroll
        for (int ct = 0; ct < 4; ++ct) Ba[ct] = *(const bf16x8*)(bb + ct * 8192);
        u16x8 pk;
        #pragma unroll
        for (int j = 0; j < 8; ++j) { xsq_p += xv[j] * xv[j]; pk[j] = f2bf(xv[j]); }
        *(u16x8*)wslot = pk;
    }
    __syncthreads();

    f32x4 acc[4][4];
    #pragma unroll
    for (int rt = 0; rt < 4; ++rt)
        #pragma unroll
        for (int ct = 0; ct < 4; ++ct)
            acc[rt][ct] = (f32x4){0.f, 0.f, 0.f, 0.f};

    // ---- fused K-loop: 8 chunk-pairs; MFMA pair p, stage pair p+1 ----
    #pragma unroll
    for (int p = 0; p < 8; ++p) {
        const int k0 = 2 * p, k1 = k0 + 1;

        if (p < 7) xv = *(const f32x8*)(xr + 64 * p + 64 + 8 * oin);  // pair p+1

        // -- chunk k0 (even): Bb prefetch for k1 interleaved with MFMAs --
        {
            bf16x8 A0 = *(const bf16x8*)(ab + k0 * 2048);
            bf16x8 A1 = *(const bf16x8*)(ab + k0 * 2048 + 512);
            #pragma unroll
            for (int ct = 0; ct < 4; ++ct) {
                Bb[ct] = *(const bf16x8*)(bb + ct * 8192 + k1 * 512);
                acc[0][ct] = MFMA(A0, Ba[ct], acc[0][ct]);
                acc[1][ct] = MFMA(A1, Ba[ct], acc[1][ct]);
            }
            bf16x8 A2 = *(const bf16x8*)(ab + k0 * 2048 + 1024);
            bf16x8 A3 = *(const bf16x8*)(ab + k0 * 2048 + 1536);
            #pragma unroll
            for (int ct = 0; ct < 4; ++ct) {
                acc[2][ct] = MFMA(A2, Ba[ct], acc[2][ct]);
                acc[3][ct] = MFMA(A3, Ba[ct], acc[3][ct]);
            }
        }
        // -- chunk k1 (odd): Ba prefetch for next pair's even chunk --
        {
            bf16x8 A0 = *(const bf16x8*)(ab + k1 * 2048);
            bf16x8 A1 = *(const bf16x8*)(ab + k1 * 2048 + 512);
            #pragma unroll
            for (int ct = 0; ct < 4; ++ct) {
                if (p < 7) Ba[ct] = *(const bf16x8*)(bb + ct * 8192 + (k0 + 2) * 512);
                acc[0][ct] = MFMA(A0, Bb[ct], acc[0][ct]);
                acc[1][ct] = MFMA(A1, Bb[ct], acc[1][ct]);
            }
            bf16x8 A2 = *(const bf16x8*)(ab + k1 * 2048 + 1024);
            bf16x8 A3 = *(const bf16x8*)(ab + k1 * 2048 + 1536);
            #pragma unroll
            for (int ct = 0; ct < 4; ++ct) {
                acc[2][ct] = MFMA(A2, Bb[ct], acc[2][ct]);
                acc[3][ct] = MFMA(A3, Bb[ct], acc[3][ct]);
            }
        }
        // -- stage pair p+1 into its LDS slot --
        if (p < 7) {
            u16x8 pk;
            #pragma unroll
            for (int j = 0; j < 8; ++j) { xsq_p += xv[j] * xv[j]; pk[j] = f2bf(xv[j]); }
            *(u16x8*)(wslot + 4096 * (p + 1)) = pk;
            __syncthreads();
        }
    }

    // ---- xsq finalize (cross-thread within row: oin = t&7 = lane&7) ----
    xsq_p += __shfl_xor(xsq_p, 1);
    xsq_p += __shfl_xor(xsq_p, 2);
    xsq_p += __shfl_xor(xsq_p, 4);
    if (oin == 0) xsq_lds[sr] = xsq_p;
    __syncthreads();

    // ---- per-column affine params (L2-hot; after K-loop on purpose) ----
    float invv[4], alf[4], bet[4];
    #pragma unroll
    for (int ct = 0; ct < 4; ++ct) {
        const int col = 64 * w + 16 * ct + r16;
        invv[ct] = invv_a[col];
        alf[ct]  = alpha_a[col];
        bet[ct]  = beta_a[col];
    }
    float xsq[4][4];
    #pragma unroll
    for (int rt = 0; rt < 4; ++rt)
        #pragma unroll
        for (int reg = 0; reg < 4; ++reg)
            xsq[rt][reg] = xsq_lds[16 * rt + 4 * h + reg];

    // ---- logits + per-row max (C layout: col=lane&15, row=4*(lane>>4)+reg) ----
    float mr[4][4];
    #pragma unroll
    for (int rt = 0; rt < 4; ++rt) {
        #pragma unroll
        for (int reg = 0; reg < 4; ++reg) {
            float m = -1e30f;
            #pragma unroll
            for (int ct = 0; ct < 4; ++ct) {
                const float v = acc[rt][ct][reg] * invv[ct] + (alf[ct] * xsq[rt][reg] + bet[ct]);
                acc[rt][ct][reg] = v;
                m = fmaxf(m, v);
            }
            m = fmaxf(m, __shfl_xor(m, 1));
            m = fmaxf(m, __shfl_xor(m, 2));
            m = fmaxf(m, __shfl_xor(m, 4));
            m = fmaxf(m, __shfl_xor(m, 8));
            mr[rt][reg] = m;
        }
    }
    if (r16 == 0) {
        #pragma unroll
        for (int rt = 0; rt < 4; ++rt)
            #pragma unroll
            for (int reg = 0; reg < 4; ++reg)
                pmax[w][16 * rt + 4 * h + reg] = mr[rt][reg];
    }
    __syncthreads();

    // ---- exp + per-row sum ----
    float sr_[4][4];
    #pragma unroll
    for (int rt = 0; rt < 4; ++rt) {
        #pragma unroll
        for (int reg = 0; reg < 4; ++reg) {
            const int rl = 16 * rt + 4 * h + reg;
            float m = pmax[0][rl];
            #pragma unroll
            for (int ww = 1; ww < 8; ++ww) m = fmaxf(m, pmax[ww][rl]);
            float s = 0.f;
            #pragma unroll
            for (int ct = 0; ct < 4; ++ct) {
                const float e = __expf(acc[rt][ct][reg] - m);
                acc[rt][ct][reg] = e;
                s += e;
            }
            s += __shfl_xor(s, 1);
            s += __shfl_xor(s, 2);
            s += __shfl_xor(s, 4);
            s += __shfl_xor(s, 8);
            sr_[rt][reg] = s;
        }
    }
    if (r16 == 0) {
        #pragma unroll
        for (int rt = 0; rt < 4; ++rt)
            #pragma unroll
            for (int reg = 0; reg < 4; ++reg)
                psum[w][16 * rt + 4 * h + reg] = sr_[rt][reg];
    }
    __syncthreads();

    // ---- normalize + store ----
    #pragma unroll
    for (int rt = 0; rt < 4; ++rt) {
        #pragma unroll
        for (int reg = 0; reg < 4; ++reg) {
            const int rl = 16 * rt + 4 * h + reg;
            float tot = psum[0][rl];
            #pragma unroll
            for (int ww = 1; ww < 8; ++ww) tot += psum[ww][rl];
            const float rinv = 1.0f / tot;
            float* orow = out + (size_t)(row0 + rl) * KCLS + 64 * w + r16;
            #pragma unroll
            for (int ct = 0; ct < 4; ++ct)
                orow[16 * ct] = acc[rt][ct][reg] * rinv;
        }
    }
}

extern "C" void kernel_launch(void* const* d_in, const int* in_sizes, int n_in,
                              void* d_out, int out_size, void* d_ws, size_t ws_size,
                              hipStream_t stream) {
    (void)in_sizes; (void)n_in; (void)out_size; (void)ws_size;
    const float* x           = (const float*)d_in[0];
    const float* means       = (const float*)d_in[1];
    const float* log_vars    = (const float*)d_in[2];
    const float* log_weights = (const float*)d_in[3];
    float* out = (float*)d_out;

    // ws: [0, 512KB) swizzled bf16 means; then inv_var/alpha/beta (512 f32 each)
    uint16_t* Bsw = (uint16_t*)d_ws;
    float* invv_a  = (float*)((char*)d_ws + (512u << 10));
    float* alpha_a = invv_a + KCLS;
    float* beta_a  = alpha_a + KCLS;

    gmm_prep<<<KCLS / 4, 256, 0, stream>>>(means, log_vars, log_weights,
                                           Bsw, invv_a, alpha_a, beta_a);
    gmm_main<<<BATCH / 64, 512, 0, stream>>>(x, Bsw, invv_a, alpha_a, beta_a, out);
}

// Round 3
// 157.434 us; speedup vs baseline: 1.1474x; 1.1474x over previous
//
#include <hip/hip_runtime.h>
#include <stdint.h>

#define BATCH 32768
#define DIM   512
#define KCLS  512

typedef __bf16    bf16x8 __attribute__((ext_vector_type(8)));
typedef float     f32x4  __attribute__((ext_vector_type(4)));
typedef float     f32x8  __attribute__((ext_vector_type(8)));
typedef uint16_t  u16x8  __attribute__((ext_vector_type(8)));

__device__ __forceinline__ uint16_t f2bf(float f) {
    // RTNE fp32 -> bf16
    uint32_t u = __float_as_uint(f);
    u += 0x7FFFu + ((u >> 16) & 1u);
    return (uint16_t)(u >> 16);
}

#define MFMA(a, b, c) __builtin_amdgcn_mfma_f32_16x16x32_bf16((a), (b), (c), 0, 0, 0)

// ---------------------------------------------------------------------------
// Prep: means (K x D fp32) -> bf16 pre-swizzled into MFMA B-fragment order.
// B-frag for mfma_f32_16x16x32_bf16: B[k = 8*(lane>>4)+j][n = lane&15].
// Bsw layout: index = (((c16*16 + ch)*64) + lane)*8, col = 16*c16 + (lane&15),
// k = 32*ch + 8*(lane>>4) + j.  Also computes inv_var/alpha/beta per class.
// ---------------------------------------------------------------------------
__global__ __launch_bounds__(256) void gmm_prep(
    const float* __restrict__ means,
    const float* __restrict__ log_vars,
    const float* __restrict__ log_weights,
    uint16_t* __restrict__ Bsw,
    float* __restrict__ invv_a,
    float* __restrict__ alpha_a,
    float* __restrict__ beta_a)
{
    const int k = blockIdx.x * 4 + (threadIdx.x >> 6);  // class index
    const int l = threadIdx.x & 63;                     // lane: elems 8l..8l+7

    const float* mrow = means + (size_t)k * DIM + l * 8;
    f32x4 v0 = *(const f32x4*)(mrow);
    f32x4 v1 = *(const f32x4*)(mrow + 4);

    u16x8 pk;
    pk[0] = f2bf(v0[0]); pk[1] = f2bf(v0[1]); pk[2] = f2bf(v0[2]); pk[3] = f2bf(v0[3]);
    pk[4] = f2bf(v1[0]); pk[5] = f2bf(v1[1]); pk[6] = f2bf(v1[2]); pk[7] = f2bf(v1[3]);

    const int c16 = k >> 4, r = k & 15, ch = l >> 2, hh = l & 3;
    *(u16x8*)(Bsw + ((((c16 * 16) + ch) * 64) + (hh * 16 + r)) * 8) = pk;

    float sq = v0[0]*v0[0] + v0[1]*v0[1] + v0[2]*v0[2] + v0[3]*v0[3]
             + v1[0]*v1[0] + v1[1]*v1[1] + v1[2]*v1[2] + v1[3]*v1[3];
    #pragma unroll
    for (int m = 1; m <= 32; m <<= 1) sq += __shfl_xor(sq, m);

    if (l == 0) {
        const float lv = log_vars[k];
        const float iv = __expf(-lv);
        invv_a[k]  = iv;
        alpha_a[k] = -0.5f * iv;
        beta_a[k]  = -0.5f * (sq * iv + (float)DIM * lv) + log_weights[k];
    }
}

// ---------------------------------------------------------------------------
// Main fused kernel, R7 = R4 structure with the register budget cut to fit
// 4 waves/SIMD.
// Unified-regfile model calibrated on R4/R5/R6:
//   R4: 104 VGPR + 64 AGPR = 168 -> 3 waves/SIMD, 47us (best)
//   R5: 128+128 = 256 -> 2 waves/SIMD, 55us
//   R6: cap 128, demand ~190 -> scratch spills (WRITE_SIZE 65->180MB), 91us
// R4 is latency-bound (MfmaUtil 13 / VALUBusy 18 / HBM 27% all idle; ~27us
// of stall in a 47us kernel). Lever: 4th wave per SIMD. Requires <=128
// unified = 64 AGPR (acc, irreducible) + <=64 VGPR:
//   * B prefetch at HALF-chunk granularity: Bc[4]+Bn[4]=32 VGPR (was 64),
//     next-half loads interleaved 1:1 with current-half MFMAs.
//   * No A double-buffer (A0/A1 = 8 VGPR; LDS latency covered by TLP).
//   * __launch_bounds__(256,4). 256-thr blocks degrade safely: if the
//     allocator misses 64 VGPR slightly, worst case = R4's 3 blocks/CU.
// Everything else (layouts, staging, epilogue) is R4 verbatim.
// ---------------------------------------------------------------------------
__global__ __launch_bounds__(256, 4) void gmm_main(
    const float* __restrict__ x,
    const uint16_t* __restrict__ Bsw,
    const float* __restrict__ invv_a,
    const float* __restrict__ alpha_a,
    const float* __restrict__ beta_a,
    float* __restrict__ out)
{
    __shared__ uint16_t As[16384];   // 32 KB
    __shared__ float xsq_lds[32];
    __shared__ float pmax[4][32];
    __shared__ float psum[4][32];

    const int t    = threadIdx.x;
    const int w    = t >> 6;        // wave -> col group (128 cols)
    const int lane = t & 63;
    const int r16  = lane & 15;
    const int h    = lane >> 4;
    const int row0 = blockIdx.x * 32;

    // ---- stage x tile -> LDS (fragment order) + xsq ----
    {
        const int srow = t >> 3, sp = t & 7;         // 8 threads per row
        const int rt_s = srow >> 4, r16_s = srow & 15;
        const float* xr = x + (size_t)(row0 + srow) * DIM;
        float xsq_p = 0.f;
        #pragma unroll
        for (int i = 0; i < 8; ++i) {
            const int o = sp + 8 * i;                // k-octet 0..63
            f32x8 v = *(const f32x8*)(xr + 8 * o);
            u16x8 pk;
            #pragma unroll
            for (int j = 0; j < 8; ++j) { xsq_p += v[j] * v[j]; pk[j] = f2bf(v[j]); }
            const int c = o >> 2, hh = o & 3;
            *(u16x8*)&As[(((c * 2 + rt_s) * 64) + hh * 16 + r16_s) * 8] = pk;
        }
        xsq_p += __shfl_xor(xsq_p, 1);
        xsq_p += __shfl_xor(xsq_p, 2);
        xsq_p += __shfl_xor(xsq_p, 4);
        if (sp == 0) xsq_lds[srow] = xsq_p;
    }
    __syncthreads();

    f32x4 acc[2][8];
    #pragma unroll
    for (int rt = 0; rt < 2; ++rt)
        #pragma unroll
        for (int ct = 0; ct < 8; ++ct)
            acc[rt][ct] = (f32x4){0.f, 0.f, 0.f, 0.f};

    const uint16_t* bb = Bsw + (size_t)w * 65536 + (size_t)lane * 8;
    const uint16_t* ab = As + (size_t)lane * 8;     // LDS, frag base

    // ---- K-loop: 16 chunks, half-chunk rotating B prefetch (Bc/Bn) ----
    bf16x8 Bc[4], Bn[4];
    #pragma unroll
    for (int q = 0; q < 4; ++q) Bc[q] = *(const bf16x8*)(bb + q * 8192);

    #pragma unroll
    for (int c = 0; c < 16; ++c) {
        bf16x8 A0 = *(const bf16x8*)(ab + c * 1024);
        bf16x8 A1 = *(const bf16x8*)(ab + c * 1024 + 512);

        // half 0 (ct 0..3): prefetch half 1 of this chunk, interleaved
        #pragma unroll
        for (int q = 0; q < 4; ++q) {
            Bn[q] = *(const bf16x8*)(bb + (q + 4) * 8192 + c * 512);
            acc[0][q] = MFMA(A0, Bc[q], acc[0][q]);
            acc[1][q] = MFMA(A1, Bc[q], acc[1][q]);
        }
        // half 1 (ct 4..7): prefetch half 0 of next chunk, interleaved
        #pragma unroll
        for (int q = 0; q < 4; ++q) {
            if (c < 15) Bc[q] = *(const bf16x8*)(bb + q * 8192 + (c + 1) * 512);
            acc[0][q + 4] = MFMA(A0, Bn[q], acc[0][q + 4]);
            acc[1][q + 4] = MFMA(A1, Bn[q], acc[1][q + 4]);
        }
    }

    // ---- per-column affine params (L2-hot; after K-loop on purpose) ----
    float invv[8], alf[8], bet[8];
    #pragma unroll
    for (int ct = 0; ct < 8; ++ct) {
        const int col = 128 * w + 16 * ct + r16;
        invv[ct] = invv_a[col];
        alf[ct]  = alpha_a[col];
        bet[ct]  = beta_a[col];
    }
    float xsq[2][4];
    #pragma unroll
    for (int rt = 0; rt < 2; ++rt)
        #pragma unroll
        for (int reg = 0; reg < 4; ++reg)
            xsq[rt][reg] = xsq_lds[16 * rt + 4 * h + reg];

    // ---- logits + per-row max (C layout: col=lane&15, row=4*(lane>>4)+reg) ----
    float mr[2][4];
    #pragma unroll
    for (int rt = 0; rt < 2; ++rt) {
        #pragma unroll
        for (int reg = 0; reg < 4; ++reg) {
            float m = -1e30f;
            #pragma unroll
            for (int ct = 0; ct < 8; ++ct) {
                const float v = acc[rt][ct][reg] * invv[ct] + (alf[ct] * xsq[rt][reg] + bet[ct]);
                acc[rt][ct][reg] = v;
                m = fmaxf(m, v);
            }
            m = fmaxf(m, __shfl_xor(m, 1));
            m = fmaxf(m, __shfl_xor(m, 2));
            m = fmaxf(m, __shfl_xor(m, 4));
            m = fmaxf(m, __shfl_xor(m, 8));
            mr[rt][reg] = m;
        }
    }
    if (r16 == 0) {
        #pragma unroll
        for (int rt = 0; rt < 2; ++rt)
            #pragma unroll
            for (int reg = 0; reg < 4; ++reg)
                pmax[w][16 * rt + 4 * h + reg] = mr[rt][reg];
    }
    __syncthreads();

    // ---- exp + per-row sum ----
    float sr[2][4];
    #pragma unroll
    for (int rt = 0; rt < 2; ++rt) {
        #pragma unroll
        for (int reg = 0; reg < 4; ++reg) {
            const int rl = 16 * rt + 4 * h + reg;
            const float m = fmaxf(fmaxf(pmax[0][rl], pmax[1][rl]),
                                  fmaxf(pmax[2][rl], pmax[3][rl]));
            float s = 0.f;
            #pragma unroll
            for (int ct = 0; ct < 8; ++ct) {
                const float e = __expf(acc[rt][ct][reg] - m);
                acc[rt][ct][reg] = e;
                s += e;
            }
            s += __shfl_xor(s, 1);
            s += __shfl_xor(s, 2);
            s += __shfl_xor(s, 4);
            s += __shfl_xor(s, 8);
            sr[rt][reg] = s;
        }
    }
    if (r16 == 0) {
        #pragma unroll
        for (int rt = 0; rt < 2; ++rt)
            #pragma unroll
            for (int reg = 0; reg < 4; ++reg)
                psum[w][16 * rt + 4 * h + reg] = sr[rt][reg];
    }
    __syncthreads();

    // ---- normalize + store ----
    #pragma unroll
    for (int rt = 0; rt < 2; ++rt) {
        #pragma unroll
        for (int reg = 0; reg < 4; ++reg) {
            const int rl = 16 * rt + 4 * h + reg;
            const float tot = (psum[0][rl] + psum[1][rl]) + (psum[2][rl] + psum[3][rl]);
            const float rinv = 1.0f / tot;
            float* orow = out + (size_t)(row0 + rl) * KCLS + 128 * w + r16;
            #pragma unroll
            for (int ct = 0; ct < 8; ++ct)
                orow[16 * ct] = acc[rt][ct][reg] * rinv;
        }
    }
}

extern "C" void kernel_launch(void* const* d_in, const int* in_sizes, int n_in,
                              void* d_out, int out_size, void* d_ws, size_t ws_size,
                              hipStream_t stream) {
    (void)in_sizes; (void)n_in; (void)out_size; (void)ws_size;
    const float* x           = (const float*)d_in[0];
    const float* means       = (const float*)d_in[1];
    const float* log_vars    = (const float*)d_in[2];
    const float* log_weights = (const float*)d_in[3];
    float* out = (float*)d_out;

    // ws: [0, 512KB) swizzled bf16 means; then inv_var/alpha/beta (512 f32 each)
    uint16_t* Bsw = (uint16_t*)d_ws;
    float* invv_a  = (float*)((char*)d_ws + (512u << 10));
    float* alpha_a = invv_a + KCLS;
    float* beta_a  = alpha_a + KCLS;

    gmm_prep<<<KCLS / 4, 256, 0, stream>>>(means, log_vars, log_weights,
                                           Bsw, invv_a, alpha_a, beta_a);
    gmm_main<<<BATCH / 32, 256, 0, stream>>>(x, Bsw, invv_a, alpha_a, beta_a, out);
}